// Round 3
// baseline (50.170 us; speedup 1.0000x reference)
//
#include <hip/hip_runtime.h>

#define N_E   512
#define DIM   64
#define HW    4096        // 64*64
#define CHW   (64*HW)     // 262144
#define NPIX  131072      // 32*64*64

typedef __attribute__((ext_vector_type(8))) short  short8;   // 8 bf16 (4 VGPRs)
typedef __attribute__((ext_vector_type(4))) float  f32x4;

__device__ __forceinline__ unsigned short f2bf(float x) {
    unsigned u = __builtin_bit_cast(unsigned, x);
    return (unsigned short)((u + 0x7FFFu + ((u >> 16) & 1u)) >> 16);   // RNE
}

// One fused kernel: per-block codebook pack (L2) + MFMA scores + argmin +
// fp32 epilogue + atomic loss accumulation.
__global__ __launch_bounds__(512, 4) void vq_fused(
        const float* __restrict__ z, const float* __restrict__ cb,
        float* __restrict__ out) {
    __shared__ uint4 Blds[4096];     // 64 KB codebook bf16 B-fragments
    __shared__ float cn[N_E];        // -0.5*||c||^2
    __shared__ int   idx_lds[256];   // chosen code per pixel
    __shared__ float red[8];

    const int tid  = threadIdx.x;
    const int w    = tid >> 6;
    const int lane = tid & 63;
    const int col  = lane & 15;
    const int grp  = lane >> 4;

    const int pbase = blockIdx.x * 256;        // 256 pixels/block, single b
    const int b     = pbase >> 12;
    const int hwp   = (pbase & 4095) + w * 32 + col;
    const float* zp = z + (size_t)b * CHW + hwp;   // + m*16 + k*HW

    // --- z loads: independent, issued first so they overlap the L2 pack ---
    float zf[2][2][8];
    #pragma unroll
    for (int m = 0; m < 2; ++m)
        #pragma unroll
        for (int h = 0; h < 2; ++h)
            #pragma unroll
            for (int j = 0; j < 8; ++j)
                zf[m][h][j] = zp[m * 16 + (h * 32 + grp * 8 + j) * HW];

    // --- pack codebook (L2-resident) into LDS, B-fragment order ---
    // frag g: 8 bf16 = cb[(g>>7)*16 + (g&15)][((g>>6)&1)*32 + ((g&63)>>4)*8 + j]
    #pragma unroll
    for (int i = 0; i < 8; ++i) {
        int g    = tid + i * 512;
        int tile = g >> 7;
        int hh   = (g >> 6) & 1;
        int ln   = g & 63;
        const float* src = cb + (tile * 16 + (ln & 15)) * DIM + hh * 32 + (ln >> 4) * 8;
        float4 a  = *(const float4*)src;
        float4 bq = *(const float4*)(src + 4);
        uint4 o;
        o.x = (unsigned)f2bf(a.x)  | ((unsigned)f2bf(a.y)  << 16);
        o.y = (unsigned)f2bf(a.z)  | ((unsigned)f2bf(a.w)  << 16);
        o.z = (unsigned)f2bf(bq.x) | ((unsigned)f2bf(bq.y) << 16);
        o.w = (unsigned)f2bf(bq.z) | ((unsigned)f2bf(bq.w) << 16);
        Blds[g] = o;
    }
    {   // cn[tid] = -0.5*||c_tid||^2 (512 threads == 512 codes, L2 reads)
        const float4* c = (const float4*)(cb + tid * DIM);
        float s = 0.f;
        #pragma unroll
        for (int k = 0; k < DIM / 4; ++k) {
            float4 v = c[k];
            s += v.x * v.x + v.y * v.y + v.z * v.z + v.w * v.w;
        }
        cn[tid] = -0.5f * s;
    }

    // --- bf16 A-fragments from the (already loaded) z values ---
    short8 afr[2][2];
    #pragma unroll
    for (int m = 0; m < 2; ++m)
        #pragma unroll
        for (int h = 0; h < 2; ++h)
            #pragma unroll
            for (int j = 0; j < 8; ++j)
                afr[m][h][j] = (short)f2bf(zf[m][h][j]);

    __syncthreads();

    // --- MFMA score loop: argmax of (z.c - 0.5||c||^2) == argmin distance ---
    float best[2][4];
    int   bid[2][4];
    #pragma unroll
    for (int m = 0; m < 2; ++m)
        #pragma unroll
        for (int r = 0; r < 4; ++r) { best[m][r] = -1e30f; bid[m][r] = 0; }

    const short8* B8 = (const short8*)Blds;
    #pragma unroll 2
    for (int t = 0; t < 32; ++t) {
        const float c0 = cn[t * 16 + col];
        f32x4 a0 = {c0, c0, c0, c0};
        f32x4 a1 = {c0, c0, c0, c0};
        short8 b0 = B8[t * 128 + lane];
        short8 b1 = B8[t * 128 + 64 + lane];
        a0 = __builtin_amdgcn_mfma_f32_16x16x32_bf16(afr[0][0], b0, a0, 0, 0, 0);
        a0 = __builtin_amdgcn_mfma_f32_16x16x32_bf16(afr[0][1], b1, a0, 0, 0, 0);
        a1 = __builtin_amdgcn_mfma_f32_16x16x32_bf16(afr[1][0], b0, a1, 0, 0, 0);
        a1 = __builtin_amdgcn_mfma_f32_16x16x32_bf16(afr[1][1], b1, a1, 0, 0, 0);
        #pragma unroll
        for (int r = 0; r < 4; ++r) {
            if (a0[r] > best[0][r]) { best[0][r] = a0[r]; bid[0][r] = t; }
            if (a1[r] > best[1][r]) { best[1][r] = a1[r]; bid[1][r] = t; }
        }
    }

    // --- cross-lane argmax over 16 code-cols; tie -> smaller code index ---
    #pragma unroll
    for (int m = 0; m < 2; ++m)
        #pragma unroll
        for (int r = 0; r < 4; ++r) {
            float s = best[m][r];
            int   c = bid[m][r] * 16 + col;
            #pragma unroll
            for (int mk = 1; mk < 16; mk <<= 1) {
                float os = __shfl_xor(s, mk);
                int   oc = __shfl_xor(c, mk);
                if (os > s || (os == s && oc < c)) { s = os; c = oc; }
            }
            if (col == 0) idx_lds[w * 32 + m * 16 + grp * 4 + r] = c;
        }
    __syncthreads();

    // --- epilogue: write q (exact fp32 from codebook) + exact fp32 loss ---
    float ls = 0.f;
    float* ob = out + 1 + (size_t)b * CHW + hwp;
    #pragma unroll
    for (int m = 0; m < 2; ++m) {
        const int qi = idx_lds[w * 32 + m * 16 + col];
        const float* qp = cb + qi * DIM + grp * 8;
        #pragma unroll
        for (int h = 0; h < 2; ++h) {
            float4 qa = *(const float4*)(qp + h * 32);
            float4 qb = *(const float4*)(qp + h * 32 + 4);
            float q[8] = {qa.x, qa.y, qa.z, qa.w, qb.x, qb.y, qb.z, qb.w};
            #pragma unroll
            for (int j = 0; j < 8; ++j) {
                float d = zf[m][h][j] - q[j];
                ls = fmaf(d, d, ls);
                ob[m * 16 + (h * 32 + grp * 8 + j) * HW] = q[j];
            }
        }
    }

    #pragma unroll
    for (int off = 32; off; off >>= 1) ls += __shfl_down(ls, off);
    if (lane == 0) red[w] = ls;
    __syncthreads();
    if (tid == 0) {
        float s = 0.f;
        #pragma unroll
        for (int i = 0; i < 8; ++i) s += red[i];
        atomicAdd(out, s * (1.25f / (float)(NPIX * DIM)));
    }
}

extern "C" void kernel_launch(void* const* d_in, const int* in_sizes, int n_in,
                              void* d_out, int out_size, void* d_ws, size_t ws_size,
                              hipStream_t stream) {
    const float* z  = (const float*)d_in[0];   // (32,64,64,64) f32
    const float* cb = (const float*)d_in[1];   // (512,64) f32
    float* out = (float*)d_out;                // [loss | zq]

    hipMemsetAsync(out, 0, sizeof(float), stream);   // zero the loss slot
    vq_fused<<<512, 512, 0, stream>>>(z, cb, out);
}